// Round 13
// baseline (303.373 us; speedup 1.0000x reference)
//
#include <hip/hip_runtime.h>

#define N_NODES   50000
#define N_EDGES   800000
#define IN_CH     128
#define HID       64
#define N_GRAPHS  64
#define N_CLASSES 2
#define NBLK_SCAN ((N_NODES + 255) / 256)   // 196
#define NREP      32                        // pooledSum replicas
#define FILL_CHUNKS ((N_EDGES + 2047) / 2048)     // 391
#define DEG_BLOCKS (FILL_CHUNKS * 8)              // 3128
#define GEMM1_BLOCKS ((N_NODES + 127) / 128)      // 391

// Round 3: single-block scan 133us -> 3-phase scan.
// Round 4: pool 59us @2.3% occupancy -> atomic partial pool + finalize.
// Round 5: fill 54us (16x write amplification) -> XCD-partitioned fill
//   (works BECAUSE part = blockIdx&7 == physical XCD round-robin).
// Round 7->8: agg2+pool fusion + 32 replicas (86->47us).
// Round 9: deg||gemm1 fusion regressed (32KB LDS reserved by ALL blocks).
// Round 11: fill||gemm1 interleave broke fill_bid&7 != blockIdx&7 -> write
// amplification returned (65MB); float2 agg saved ~40us (hidden by that).
// Round 12/13: fill blocks FIRST (fill_bid = blockIdx, XCD-aligned), LDS-free
// gemm1 blocks appended at tail. (Round 12 bench timed out; resubmitted.)

// ---------------------------------------------------------------------------
// K0: in-degree count, XCD-partitioned + dst-windowed.
// ---------------------------------------------------------------------------
__global__ __launch_bounds__(256) void deg_kernel(const int* __restrict__ ei,
                                                  int* __restrict__ degCount) {
    int part = blockIdx.x & 7;
    int blk  = blockIdx.x >> 3;                   // 0..390
    int lo   = part * 6250;
    int hi   = lo + 6250;
#pragma unroll
    for (int it = 0; it < 8; ++it) {
        int e = blk * 2048 + it * 256 + (int)threadIdx.x;
        if (e < N_EDGES) {
            int dst = ei[N_EDGES + e];
            if (dst >= lo && dst < hi) atomicAdd(&degCount[dst], 1);
        }
    }
}

// ---------------------------------------------------------------------------
// K1a/b/c: 3-phase scan
// ---------------------------------------------------------------------------
__global__ __launch_bounds__(256) void scan1_kernel(const int* __restrict__ degCount,
                                                    int* __restrict__ blockSums) {
    __shared__ int red[256];
    int i = blockIdx.x * 256 + threadIdx.x;
    red[threadIdx.x] = (i < N_NODES) ? degCount[i] : 0;
    __syncthreads();
    for (int off = 128; off > 0; off >>= 1) {
        if (threadIdx.x < off) red[threadIdx.x] += red[threadIdx.x + off];
        __syncthreads();
    }
    if (threadIdx.x == 0) blockSums[blockIdx.x] = red[0];
}

__global__ __launch_bounds__(256) void scan2_kernel(int* __restrict__ blockSums) {
    __shared__ int s[256];
    int t = threadIdx.x;
    int v = (t < NBLK_SCAN) ? blockSums[t] : 0;
    s[t] = v;
    __syncthreads();
    for (int off = 1; off < 256; off <<= 1) {
        int a = (t >= off) ? s[t - off] : 0;
        __syncthreads();
        s[t] += a;
        __syncthreads();
    }
    if (t < NBLK_SCAN) blockSums[t] = s[t] - v;   // exclusive prefix
}

__global__ __launch_bounds__(256) void scan3_kernel(int* __restrict__ degFill,
                                                    const int* __restrict__ blockSums,
                                                    int* __restrict__ rowPtr,
                                                    float* __restrict__ dinv) {
    __shared__ int s[256];
    int t = threadIdx.x;
    int i = blockIdx.x * 256 + t;
    int d = (i < N_NODES) ? degFill[i] : 0;
    s[t] = d;
    __syncthreads();
    for (int off = 1; off < 256; off <<= 1) {
        int a = (t >= off) ? s[t - off] : 0;
        __syncthreads();
        s[t] += a;
        __syncthreads();
    }
    int excl = s[t] - d + blockSums[blockIdx.x];
    if (i < N_NODES) {
        rowPtr[i]  = excl;
        degFill[i] = excl;
        dinv[i]    = 1.0f / sqrtf((float)(d + 1));
    }
    if (i == 0) rowPtr[N_NODES] = N_EDGES;
}

// ---------------------------------------------------------------------------
// K2: FUSED fill || gemm1, XCD-ALIGNED: blocks [0,DEG_BLOCKS) = fill with
// fill_bid == blockIdx (so part = blockIdx&7 = physical XCD, round-5
// property preserved); blocks [DEG_BLOCKS, +GEMM1_BLOCKS) = LDS-free gemm1
// (W1 via coalesced 256B L2-resident loads, 8 rows/thread).
// ---------------------------------------------------------------------------
#define FMA4(xs, w, a) { (a).x = fmaf((xs), (w).x, (a).x); \
                         (a).y = fmaf((xs), (w).y, (a).y); \
                         (a).z = fmaf((xs), (w).z, (a).z); \
                         (a).w = fmaf((xs), (w).w, (a).w); }

__global__ __launch_bounds__(256) void fill_gemm1_kernel(const int* __restrict__ ei,
                                                         int* __restrict__ fillPtr,
                                                         int* __restrict__ colIdx,
                                                         const float* __restrict__ x,
                                                         const float* __restrict__ W1,
                                                         const float* __restrict__ dinv,
                                                         float* __restrict__ out) {
    if (blockIdx.x < DEG_BLOCKS) {
        // ---- fill role (XCD-aligned) ----
        int part = blockIdx.x & 7;
        int blk  = blockIdx.x >> 3;
        int lo   = part * 6250;
        int hi   = lo + 6250;
#pragma unroll
        for (int it = 0; it < 8; ++it) {
            int e = blk * 2048 + it * 256 + (int)threadIdx.x;
            if (e < N_EDGES) {
                int dst = ei[N_EDGES + e];
                if (dst >= lo && dst < hi) {
                    int src = ei[e];
                    int pos = atomicAdd(&fillPtr[dst], 1);
                    colIdx[pos] = src;
                }
            }
        }
        return;
    }
    // ---- gemm1 role ----
    int bid = blockIdx.x - DEG_BLOCKS;
    const float4* W4 = (const float4*)W1;
    const int c4   = threadIdx.x & 15;
    const int rg   = threadIdx.x >> 4;
    const int row0 = bid * 128 + rg * 8;

    const float4* ap[8];
#pragma unroll
    for (int r = 0; r < 8; ++r) {
        int rowc = min(row0 + r, N_NODES - 1);
        ap[r] = (const float4*)(x + (size_t)rowc * IN_CH);
    }

    float4 acc[8] = {};
    for (int kk = 0; kk < IN_CH / 4; ++kk) {
        float4 xv[8];
#pragma unroll
        for (int r = 0; r < 8; ++r) xv[r] = ap[r][kk];
        float4 w;
        w = W4[(4 * kk + 0) * 16 + c4];
#pragma unroll
        for (int r = 0; r < 8; ++r) FMA4(xv[r].x, w, acc[r]);
        w = W4[(4 * kk + 1) * 16 + c4];
#pragma unroll
        for (int r = 0; r < 8; ++r) FMA4(xv[r].y, w, acc[r]);
        w = W4[(4 * kk + 2) * 16 + c4];
#pragma unroll
        for (int r = 0; r < 8; ++r) FMA4(xv[r].z, w, acc[r]);
        w = W4[(4 * kk + 3) * 16 + c4];
#pragma unroll
        for (int r = 0; r < 8; ++r) FMA4(xv[r].w, w, acc[r]);
    }

#pragma unroll
    for (int r = 0; r < 8; ++r) {
        int row = row0 + r;
        if (row < N_NODES) {
            float dv = dinv[row];
            float4 o = acc[r];
            o.x *= dv; o.y *= dv; o.z *= dv; o.w *= dv;
            ((float4*)(out + (size_t)row * HID))[c4] = o;
        }
    }
}

// ---------------------------------------------------------------------------
// K5: gemm2: g2 = (h1 @ W2) * dinv[row]  (standalone, LDS-staged)
// ---------------------------------------------------------------------------
template <int K>
__global__ __launch_bounds__(256) void gemm_kernel(const float* __restrict__ A,
                                                   const float* __restrict__ W,
                                                   const float* __restrict__ dinv,
                                                   float* __restrict__ out) {
    __shared__ float4 Ws[K * 16];
    for (int i = threadIdx.x; i < K * 16; i += 256)
        Ws[i] = ((const float4*)W)[i];
    __syncthreads();

    const int c4   = threadIdx.x & 15;
    const int rg   = threadIdx.x >> 4;
    const int row0 = blockIdx.x * 128 + rg * 8;

    const float4* ap[8];
#pragma unroll
    for (int r = 0; r < 8; ++r) {
        int rowc = min(row0 + r, N_NODES - 1);
        ap[r] = (const float4*)(A + (size_t)rowc * K);
    }

    float4 acc[8] = {};
    for (int kk = 0; kk < K / 4; ++kk) {
        float4 xv[8];
#pragma unroll
        for (int r = 0; r < 8; ++r) xv[r] = ap[r][kk];
        float4 w;
        w = Ws[(4 * kk + 0) * 16 + c4];
#pragma unroll
        for (int r = 0; r < 8; ++r) FMA4(xv[r].x, w, acc[r]);
        w = Ws[(4 * kk + 1) * 16 + c4];
#pragma unroll
        for (int r = 0; r < 8; ++r) FMA4(xv[r].y, w, acc[r]);
        w = Ws[(4 * kk + 2) * 16 + c4];
#pragma unroll
        for (int r = 0; r < 8; ++r) FMA4(xv[r].z, w, acc[r]);
        w = Ws[(4 * kk + 3) * 16 + c4];
#pragma unroll
        for (int r = 0; r < 8; ++r) FMA4(xv[r].w, w, acc[r]);
    }

#pragma unroll
    for (int r = 0; r < 8; ++r) {
        int row = row0 + r;
        if (row < N_NODES) {
            float dv = dinv[row];
            float4 o = acc[r];
            o.x *= dv; o.y *= dv; o.z *= dv; o.w *= dv;
            ((float4*)(out + (size_t)row * HID))[c4] = o;
        }
    }
}

// ---------------------------------------------------------------------------
// K4: layer-1 aggregation, float2 dual-row gather (round-11 win: ~40us).
// ---------------------------------------------------------------------------
__global__ __launch_bounds__(256) void agg1_kernel(const float* __restrict__ g,
                                                   const float* __restrict__ dinv,
                                                   const int* __restrict__ rowPtr,
                                                   const int* __restrict__ colIdx,
                                                   const float* __restrict__ bias,
                                                   float* __restrict__ out) {
    int lane = threadIdx.x & 63;
    int half = lane >> 5;
    int hl   = lane & 31;
    int v = blockIdx.x * 4 + (threadIdx.x >> 6);
    if (v >= N_NODES) return;

    const float2* g2 = (const float2*)g;          // row stride = 32 float2
    float2 acc = {0.f, 0.f};
    if (half == 0) acc = g2[(size_t)v * 32 + hl]; // self term (once)

    int e0 = rowPtr[v];
    int e1 = rowPtr[v + 1];
    for (int e = e0; e < e1; e += 16) {
        int   u[8];
        float wsel[8];
#pragma unroll
        for (int k = 0; k < 8; ++k) {
            int ee  = e + 2 * k + half;
            int idx = min(ee, e1 - 1);
            u[k]    = colIdx[idx];
            wsel[k] = (ee < e1) ? 1.f : 0.f;
        }
#pragma unroll
        for (int k = 0; k < 8; ++k) {
            float2 a = g2[(size_t)u[k] * 32 + hl];
            acc.x = fmaf(wsel[k], a.x, acc.x);
            acc.y = fmaf(wsel[k], a.y, acc.y);
        }
    }
    acc.x += __shfl_xor(acc.x, 32);
    acc.y += __shfl_xor(acc.y, 32);

    float dv = dinv[v];
    float2 b = ((const float2*)bias)[hl];
    float2 r;
    r.x = fmaxf(dv * acc.x + b.x, 0.f);
    r.y = fmaxf(dv * acc.y + b.y, 0.f);
    if (half == 0) ((float2*)(out + (size_t)v * HID))[hl] = r;
}

// ---------------------------------------------------------------------------
// K6: layer-2 aggregation + replicated pool atomics, float2 dual-row gather.
// ---------------------------------------------------------------------------
__global__ __launch_bounds__(256) void agg2pool_kernel(const float* __restrict__ g,
                                                       const float* __restrict__ dinv,
                                                       const int* __restrict__ rowPtr,
                                                       const int* __restrict__ colIdx,
                                                       const float* __restrict__ bias,
                                                       const int* __restrict__ batch,
                                                       float* __restrict__ pooledSum) {
    int lane = threadIdx.x & 63;
    int half = lane >> 5;
    int hl   = lane & 31;
    int v = blockIdx.x * 4 + (threadIdx.x >> 6);
    if (v >= N_NODES) return;

    const float2* g2 = (const float2*)g;
    float2 acc = {0.f, 0.f};
    if (half == 0) acc = g2[(size_t)v * 32 + hl];

    int e0 = rowPtr[v];
    int e1 = rowPtr[v + 1];
    for (int e = e0; e < e1; e += 16) {
        int   u[8];
        float wsel[8];
#pragma unroll
        for (int k = 0; k < 8; ++k) {
            int ee  = e + 2 * k + half;
            int idx = min(ee, e1 - 1);
            u[k]    = colIdx[idx];
            wsel[k] = (ee < e1) ? 1.f : 0.f;
        }
#pragma unroll
        for (int k = 0; k < 8; ++k) {
            float2 a = g2[(size_t)u[k] * 32 + hl];
            acc.x = fmaf(wsel[k], a.x, acc.x);
            acc.y = fmaf(wsel[k], a.y, acc.y);
        }
    }
    acc.x += __shfl_xor(acc.x, 32);
    acc.y += __shfl_xor(acc.y, 32);

    float dv = dinv[v];
    float2 b = ((const float2*)bias)[hl];
    float rx = fmaxf(dv * acc.x + b.x, 0.f);
    float ry = fmaxf(dv * acc.y + b.y, 0.f);

    int gid = batch[v];                           // wave-uniform
    int rep = blockIdx.x & (NREP - 1);
    atomicAdd(&pooledSum[(size_t)rep * N_GRAPHS * HID + gid * HID + 2 * hl + half],
              half ? ry : rx);
}

// ---------------------------------------------------------------------------
// K7: finalize. Sums 32 replicas, divides by count, head via shuffle reduce.
// d_out layout: [ out (64x2) | pooled (64x64) ]
// ---------------------------------------------------------------------------
__global__ __launch_bounds__(64) void pool2_kernel(const float* __restrict__ pooledSum,
                                                   const int* __restrict__ batch,
                                                   const float* __restrict__ Wl,
                                                   const float* __restrict__ bl,
                                                   float* __restrict__ dout) {
    int g    = blockIdx.x;
    int lane = threadIdx.x;

    int lo0 = 0, hi = N_NODES;
    while (lo0 < hi) { int mid = (lo0 + hi) >> 1; if (batch[mid] < g) lo0 = mid + 1; else hi = mid; }
    int lo1 = lo0; hi = N_NODES;
    while (lo1 < hi) { int mid = (lo1 + hi) >> 1; if (batch[mid] < g + 1) lo1 = mid + 1; else hi = mid; }
    float cnt = (float)(lo1 - lo0);

    float s = 0.f;
#pragma unroll
    for (int rep = 0; rep < NREP; ++rep)
        s += pooledSum[(size_t)rep * N_GRAPHS * HID + g * HID + lane];

    float p = s / fmaxf(cnt, 1.0f);
    dout[N_GRAPHS * N_CLASSES + g * HID + lane] = p;

    float p0 = p * Wl[lane * N_CLASSES + 0];
    float p1 = p * Wl[lane * N_CLASSES + 1];
#pragma unroll
    for (int off = 32; off > 0; off >>= 1) {
        p0 += __shfl_down(p0, off, 64);
        p1 += __shfl_down(p1, off, 64);
    }
    if (lane == 0) {
        dout[g * N_CLASSES + 0] = p0 + bl[0];
        dout[g * N_CLASSES + 1] = p1 + bl[1];
    }
}

// ---------------------------------------------------------------------------
extern "C" void kernel_launch(void* const* d_in, const int* in_sizes, int n_in,
                              void* d_out, int out_size, void* d_ws, size_t ws_size,
                              hipStream_t stream) {
    const float* x     = (const float*)d_in[0];
    const int*   ei    = (const int*)d_in[1];    // int32 on device
    const int*   batch = (const int*)d_in[2];    // int32 on device
    const float* W1    = (const float*)d_in[3];
    const float* b1    = (const float*)d_in[4];
    const float* W2    = (const float*)d_in[5];
    const float* b2    = (const float*)d_in[6];
    const float* Wl    = (const float*)d_in[7];
    const float* bl    = (const float*)d_in[8];
    float* out = (float*)d_out;

    char* ws = (char*)d_ws;
    size_t off = 0;
    auto alloc = [&](size_t bytes) -> void* {
        void* p = ws + off;
        off += (bytes + 255) & ~(size_t)255;
        return p;
    };
    int*   degFill   = (int*)  alloc((size_t)N_NODES * 4);        // counts -> fillPtr
    int*   rowPtr    = (int*)  alloc((size_t)(N_NODES + 1) * 4);
    float* dinv      = (float*)alloc((size_t)N_NODES * 4);
    int*   blockSums = (int*)  alloc((size_t)NBLK_SCAN * 4);
    float* pooledSum = (float*)alloc((size_t)NREP * N_GRAPHS * HID * 4);  // 512 KB
    int*   colIdx    = (int*)  alloc((size_t)N_EDGES * 4);
    float* bufA      = (float*)alloc((size_t)N_NODES * HID * 4);  // g1, then g2
    float* bufB      = (float*)alloc((size_t)N_NODES * HID * 4);  // h1

    hipMemsetAsync(degFill, 0, (size_t)N_NODES * 4, stream);
    hipMemsetAsync(pooledSum, 0, (size_t)NREP * N_GRAPHS * HID * 4, stream);

    deg_kernel  <<<DEG_BLOCKS, 256, 0, stream>>>(ei, degFill);
    scan1_kernel<<<NBLK_SCAN, 256, 0, stream>>>(degFill, blockSums);
    scan2_kernel<<<1, 256, 0, stream>>>(blockSums);
    scan3_kernel<<<NBLK_SCAN, 256, 0, stream>>>(degFill, blockSums, rowPtr, dinv);

    // fused: fill (blocks 0..3127, XCD-aligned) || gemm1 LDS-free (tail 391)
    fill_gemm1_kernel<<<DEG_BLOCKS + GEMM1_BLOCKS, 256, 0, stream>>>(
        ei, degFill, colIdx, x, W1, dinv, bufA);

    // layer 1 aggregation
    agg1_kernel<<<N_NODES / 4, 256, 0, stream>>>(bufA, dinv, rowPtr, colIdx, b1, bufB);

    // layer 2
    gemm_kernel<HID><<<GEMM1_BLOCKS, 256, 0, stream>>>(bufB, W2, dinv, bufA);
    agg2pool_kernel <<<N_NODES / 4, 256, 0, stream>>>(bufA, dinv, rowPtr, colIdx, b2, batch, pooledSum);

    // finalize pool + head
    pool2_kernel<<<N_GRAPHS, 64, 0, stream>>>(pooledSum, batch, Wl, bl, out);
}

// Round 15
// 292.246 us; speedup vs baseline: 1.0381x; 1.0381x over previous
//
#include <hip/hip_runtime.h>

#define N_NODES   50000
#define N_EDGES   800000
#define IN_CH     128
#define HID       64
#define N_GRAPHS  64
#define N_CLASSES 2
#define NBLK_SCAN ((N_NODES + 255) / 256)   // 196
#define NREP      32                        // pooledSum replicas
#define FILL_CHUNKS ((N_EDGES + 2047) / 2048)     // 391
#define DEG_BLOCKS (FILL_CHUNKS * 8)              // 3128
#define GEMM_BLOCKS ((N_NODES + 127) / 128)       // 391

// Round 3: single-block scan 133us -> 3-phase scan.
// Round 4: pool 59us @2.3% occupancy -> atomic partial pool + finalize.
// Round 5: fill 54us (16x write amplification) -> XCD-partitioned fill.
// Round 7->8: agg2+pool fusion + 32 replicas (86->47us).
// Round 9/11/13: THREE fill/gemm1 fusion attempts all regressed (LDS blanket
// reservation; broken XCD alignment; late-block XCD drift + tail serialization).
// Fusion abandoned per decision rule. Round 11's float2 dual-row agg saved
// ~40us (verified by A/B against the masked regression).
// Round 14/15: round-10 separate-kernel structure + round-11 float2 agg
// kernels. (Round 14 bench timed out; resubmitted unchanged.)

// ---------------------------------------------------------------------------
// K0: in-degree count, XCD-partitioned + dst-windowed.
// ---------------------------------------------------------------------------
__global__ __launch_bounds__(256) void deg_kernel(const int* __restrict__ ei,
                                                  int* __restrict__ degCount) {
    int part = blockIdx.x & 7;
    int blk  = blockIdx.x >> 3;                   // 0..390
    int lo   = part * 6250;
    int hi   = lo + 6250;
#pragma unroll
    for (int it = 0; it < 8; ++it) {
        int e = blk * 2048 + it * 256 + (int)threadIdx.x;
        if (e < N_EDGES) {
            int dst = ei[N_EDGES + e];
            if (dst >= lo && dst < hi) atomicAdd(&degCount[dst], 1);
        }
    }
}

// ---------------------------------------------------------------------------
// K1a/b/c: 3-phase scan
// ---------------------------------------------------------------------------
__global__ __launch_bounds__(256) void scan1_kernel(const int* __restrict__ degCount,
                                                    int* __restrict__ blockSums) {
    __shared__ int red[256];
    int i = blockIdx.x * 256 + threadIdx.x;
    red[threadIdx.x] = (i < N_NODES) ? degCount[i] : 0;
    __syncthreads();
    for (int off = 128; off > 0; off >>= 1) {
        if (threadIdx.x < off) red[threadIdx.x] += red[threadIdx.x + off];
        __syncthreads();
    }
    if (threadIdx.x == 0) blockSums[blockIdx.x] = red[0];
}

__global__ __launch_bounds__(256) void scan2_kernel(int* __restrict__ blockSums) {
    __shared__ int s[256];
    int t = threadIdx.x;
    int v = (t < NBLK_SCAN) ? blockSums[t] : 0;
    s[t] = v;
    __syncthreads();
    for (int off = 1; off < 256; off <<= 1) {
        int a = (t >= off) ? s[t - off] : 0;
        __syncthreads();
        s[t] += a;
        __syncthreads();
    }
    if (t < NBLK_SCAN) blockSums[t] = s[t] - v;   // exclusive prefix
}

__global__ __launch_bounds__(256) void scan3_kernel(int* __restrict__ degFill,
                                                    const int* __restrict__ blockSums,
                                                    int* __restrict__ rowPtr,
                                                    float* __restrict__ dinv) {
    __shared__ int s[256];
    int t = threadIdx.x;
    int i = blockIdx.x * 256 + t;
    int d = (i < N_NODES) ? degFill[i] : 0;
    s[t] = d;
    __syncthreads();
    for (int off = 1; off < 256; off <<= 1) {
        int a = (t >= off) ? s[t - off] : 0;
        __syncthreads();
        s[t] += a;
        __syncthreads();
    }
    int excl = s[t] - d + blockSums[blockIdx.x];
    if (i < N_NODES) {
        rowPtr[i]  = excl;
        degFill[i] = excl;
        dinv[i]    = 1.0f / sqrtf((float)(d + 1));
    }
    if (i == 0) rowPtr[N_NODES] = N_EDGES;
}

// ---------------------------------------------------------------------------
// K2: CSR fill, XCD-partitioned + dst-windowed (round-5 fix, standalone).
// ---------------------------------------------------------------------------
__global__ __launch_bounds__(256) void fill_kernel(const int* __restrict__ ei,
                                                   int* __restrict__ fillPtr,
                                                   int* __restrict__ colIdx) {
    int part = blockIdx.x & 7;
    int blk  = blockIdx.x >> 3;
    int lo   = part * 6250;
    int hi   = lo + 6250;
#pragma unroll
    for (int it = 0; it < 8; ++it) {
        int e = blk * 2048 + it * 256 + (int)threadIdx.x;
        if (e < N_EDGES) {
            int dst = ei[N_EDGES + e];
            if (dst >= lo && dst < hi) {
                int src = ei[e];
                int pos = atomicAdd(&fillPtr[dst], 1);
                colIdx[pos] = src;
            }
        }
    }
}

// ---------------------------------------------------------------------------
// K3/K5: g = (A @ W) * dinv[row]  (LDS-staged, 8 rows/thread — round-10 form)
// ---------------------------------------------------------------------------
#define FMA4(xs, w, a) { (a).x = fmaf((xs), (w).x, (a).x); \
                         (a).y = fmaf((xs), (w).y, (a).y); \
                         (a).z = fmaf((xs), (w).z, (a).z); \
                         (a).w = fmaf((xs), (w).w, (a).w); }

template <int K>
__global__ __launch_bounds__(256) void gemm_kernel(const float* __restrict__ A,
                                                   const float* __restrict__ W,
                                                   const float* __restrict__ dinv,
                                                   float* __restrict__ out) {
    __shared__ float4 Ws[K * 16];
    for (int i = threadIdx.x; i < K * 16; i += 256)
        Ws[i] = ((const float4*)W)[i];
    __syncthreads();

    const int c4   = threadIdx.x & 15;
    const int rg   = threadIdx.x >> 4;
    const int row0 = blockIdx.x * 128 + rg * 8;

    const float4* ap[8];
#pragma unroll
    for (int r = 0; r < 8; ++r) {
        int rowc = min(row0 + r, N_NODES - 1);
        ap[r] = (const float4*)(A + (size_t)rowc * K);
    }

    float4 acc[8] = {};
    for (int kk = 0; kk < K / 4; ++kk) {
        float4 xv[8];
#pragma unroll
        for (int r = 0; r < 8; ++r) xv[r] = ap[r][kk];
        float4 w;
        w = Ws[(4 * kk + 0) * 16 + c4];
#pragma unroll
        for (int r = 0; r < 8; ++r) FMA4(xv[r].x, w, acc[r]);
        w = Ws[(4 * kk + 1) * 16 + c4];
#pragma unroll
        for (int r = 0; r < 8; ++r) FMA4(xv[r].y, w, acc[r]);
        w = Ws[(4 * kk + 2) * 16 + c4];
#pragma unroll
        for (int r = 0; r < 8; ++r) FMA4(xv[r].z, w, acc[r]);
        w = Ws[(4 * kk + 3) * 16 + c4];
#pragma unroll
        for (int r = 0; r < 8; ++r) FMA4(xv[r].w, w, acc[r]);
    }

#pragma unroll
    for (int r = 0; r < 8; ++r) {
        int row = row0 + r;
        if (row < N_NODES) {
            float dv = dinv[row];
            float4 o = acc[r];
            o.x *= dv; o.y *= dv; o.z *= dv; o.w *= dv;
            ((float4*)(out + (size_t)row * HID))[c4] = o;
        }
    }
}

// ---------------------------------------------------------------------------
// K4: layer-1 aggregation, float2 dual-row gather (round-11 win).
// Wave = 1 node; half 0 = even-indexed neighbors, half 1 = odd; lane loads
// float2 (channels 2hl,2hl+1); halves combined via shfl_xor(32).
// ---------------------------------------------------------------------------
__global__ __launch_bounds__(256) void agg1_kernel(const float* __restrict__ g,
                                                   const float* __restrict__ dinv,
                                                   const int* __restrict__ rowPtr,
                                                   const int* __restrict__ colIdx,
                                                   const float* __restrict__ bias,
                                                   float* __restrict__ out) {
    int lane = threadIdx.x & 63;
    int half = lane >> 5;
    int hl   = lane & 31;
    int v = blockIdx.x * 4 + (threadIdx.x >> 6);
    if (v >= N_NODES) return;

    const float2* g2 = (const float2*)g;          // row stride = 32 float2
    float2 acc = {0.f, 0.f};
    if (half == 0) acc = g2[(size_t)v * 32 + hl]; // self term (once)

    int e0 = rowPtr[v];
    int e1 = rowPtr[v + 1];
    for (int e = e0; e < e1; e += 16) {
        int   u[8];
        float wsel[8];
#pragma unroll
        for (int k = 0; k < 8; ++k) {
            int ee  = e + 2 * k + half;
            int idx = min(ee, e1 - 1);
            u[k]    = colIdx[idx];
            wsel[k] = (ee < e1) ? 1.f : 0.f;
        }
#pragma unroll
        for (int k = 0; k < 8; ++k) {
            float2 a = g2[(size_t)u[k] * 32 + hl];
            acc.x = fmaf(wsel[k], a.x, acc.x);
            acc.y = fmaf(wsel[k], a.y, acc.y);
        }
    }
    acc.x += __shfl_xor(acc.x, 32);
    acc.y += __shfl_xor(acc.y, 32);

    float dv = dinv[v];
    float2 b = ((const float2*)bias)[hl];
    float2 r;
    r.x = fmaxf(dv * acc.x + b.x, 0.f);
    r.y = fmaxf(dv * acc.y + b.y, 0.f);
    if (half == 0) ((float2*)(out + (size_t)v * HID))[hl] = r;
}

// ---------------------------------------------------------------------------
// K6: layer-2 aggregation + replicated pool atomics, float2 dual-row gather.
// ---------------------------------------------------------------------------
__global__ __launch_bounds__(256) void agg2pool_kernel(const float* __restrict__ g,
                                                       const float* __restrict__ dinv,
                                                       const int* __restrict__ rowPtr,
                                                       const int* __restrict__ colIdx,
                                                       const float* __restrict__ bias,
                                                       const int* __restrict__ batch,
                                                       float* __restrict__ pooledSum) {
    int lane = threadIdx.x & 63;
    int half = lane >> 5;
    int hl   = lane & 31;
    int v = blockIdx.x * 4 + (threadIdx.x >> 6);
    if (v >= N_NODES) return;

    const float2* g2 = (const float2*)g;
    float2 acc = {0.f, 0.f};
    if (half == 0) acc = g2[(size_t)v * 32 + hl];

    int e0 = rowPtr[v];
    int e1 = rowPtr[v + 1];
    for (int e = e0; e < e1; e += 16) {
        int   u[8];
        float wsel[8];
#pragma unroll
        for (int k = 0; k < 8; ++k) {
            int ee  = e + 2 * k + half;
            int idx = min(ee, e1 - 1);
            u[k]    = colIdx[idx];
            wsel[k] = (ee < e1) ? 1.f : 0.f;
        }
#pragma unroll
        for (int k = 0; k < 8; ++k) {
            float2 a = g2[(size_t)u[k] * 32 + hl];
            acc.x = fmaf(wsel[k], a.x, acc.x);
            acc.y = fmaf(wsel[k], a.y, acc.y);
        }
    }
    acc.x += __shfl_xor(acc.x, 32);
    acc.y += __shfl_xor(acc.y, 32);

    float dv = dinv[v];
    float2 b = ((const float2*)bias)[hl];
    float rx = fmaxf(dv * acc.x + b.x, 0.f);
    float ry = fmaxf(dv * acc.y + b.y, 0.f);

    int gid = batch[v];                           // wave-uniform
    int rep = blockIdx.x & (NREP - 1);
    atomicAdd(&pooledSum[(size_t)rep * N_GRAPHS * HID + gid * HID + 2 * hl + half],
              half ? ry : rx);
}

// ---------------------------------------------------------------------------
// K7: finalize. Sums 32 replicas, divides by count, head via shuffle reduce.
// d_out layout: [ out (64x2) | pooled (64x64) ]
// ---------------------------------------------------------------------------
__global__ __launch_bounds__(64) void pool2_kernel(const float* __restrict__ pooledSum,
                                                   const int* __restrict__ batch,
                                                   const float* __restrict__ Wl,
                                                   const float* __restrict__ bl,
                                                   float* __restrict__ dout) {
    int g    = blockIdx.x;
    int lane = threadIdx.x;

    int lo0 = 0, hi = N_NODES;
    while (lo0 < hi) { int mid = (lo0 + hi) >> 1; if (batch[mid] < g) lo0 = mid + 1; else hi = mid; }
    int lo1 = lo0; hi = N_NODES;
    while (lo1 < hi) { int mid = (lo1 + hi) >> 1; if (batch[mid] < g + 1) lo1 = mid + 1; else hi = mid; }
    float cnt = (float)(lo1 - lo0);

    float s = 0.f;
#pragma unroll
    for (int rep = 0; rep < NREP; ++rep)
        s += pooledSum[(size_t)rep * N_GRAPHS * HID + g * HID + lane];

    float p = s / fmaxf(cnt, 1.0f);
    dout[N_GRAPHS * N_CLASSES + g * HID + lane] = p;

    float p0 = p * Wl[lane * N_CLASSES + 0];
    float p1 = p * Wl[lane * N_CLASSES + 1];
#pragma unroll
    for (int off = 32; off > 0; off >>= 1) {
        p0 += __shfl_down(p0, off, 64);
        p1 += __shfl_down(p1, off, 64);
    }
    if (lane == 0) {
        dout[g * N_CLASSES + 0] = p0 + bl[0];
        dout[g * N_CLASSES + 1] = p1 + bl[1];
    }
}

// ---------------------------------------------------------------------------
extern "C" void kernel_launch(void* const* d_in, const int* in_sizes, int n_in,
                              void* d_out, int out_size, void* d_ws, size_t ws_size,
                              hipStream_t stream) {
    const float* x     = (const float*)d_in[0];
    const int*   ei    = (const int*)d_in[1];    // int32 on device
    const int*   batch = (const int*)d_in[2];    // int32 on device
    const float* W1    = (const float*)d_in[3];
    const float* b1    = (const float*)d_in[4];
    const float* W2    = (const float*)d_in[5];
    const float* b2    = (const float*)d_in[6];
    const float* Wl    = (const float*)d_in[7];
    const float* bl    = (const float*)d_in[8];
    float* out = (float*)d_out;

    char* ws = (char*)d_ws;
    size_t off = 0;
    auto alloc = [&](size_t bytes) -> void* {
        void* p = ws + off;
        off += (bytes + 255) & ~(size_t)255;
        return p;
    };
    int*   degFill   = (int*)  alloc((size_t)N_NODES * 4);        // counts -> fillPtr
    int*   rowPtr    = (int*)  alloc((size_t)(N_NODES + 1) * 4);
    float* dinv      = (float*)alloc((size_t)N_NODES * 4);
    int*   blockSums = (int*)  alloc((size_t)NBLK_SCAN * 4);
    float* pooledSum = (float*)alloc((size_t)NREP * N_GRAPHS * HID * 4);  // 512 KB
    int*   colIdx    = (int*)  alloc((size_t)N_EDGES * 4);
    float* bufA      = (float*)alloc((size_t)N_NODES * HID * 4);  // g1, then g2
    float* bufB      = (float*)alloc((size_t)N_NODES * HID * 4);  // h1

    hipMemsetAsync(degFill, 0, (size_t)N_NODES * 4, stream);
    hipMemsetAsync(pooledSum, 0, (size_t)NREP * N_GRAPHS * HID * 4, stream);

    deg_kernel  <<<DEG_BLOCKS, 256, 0, stream>>>(ei, degFill);
    scan1_kernel<<<NBLK_SCAN, 256, 0, stream>>>(degFill, blockSums);
    scan2_kernel<<<1, 256, 0, stream>>>(blockSums);
    scan3_kernel<<<NBLK_SCAN, 256, 0, stream>>>(degFill, blockSums, rowPtr, dinv);
    fill_kernel <<<DEG_BLOCKS, 256, 0, stream>>>(ei, degFill, colIdx);

    // layer 1: g1 = (x@W1)*dinv ; h1 = relu(dinv*(g1[v]+sum g1[u]) + b1)
    gemm_kernel<IN_CH><<<GEMM_BLOCKS, 256, 0, stream>>>(x, W1, dinv, bufA);
    agg1_kernel       <<<N_NODES / 4, 256, 0, stream>>>(bufA, dinv, rowPtr, colIdx, b1, bufB);

    // layer 2: g2 = (h1@W2)*dinv ; h2 row computed in-register, pooled directly
    gemm_kernel<HID><<<GEMM_BLOCKS, 256, 0, stream>>>(bufB, W2, dinv, bufA);
    agg2pool_kernel <<<N_NODES / 4, 256, 0, stream>>>(bufA, dinv, rowPtr, colIdx, b2, batch, pooledSum);

    // finalize pool + head
    pool2_kernel<<<N_GRAPHS, 64, 0, stream>>>(pooledSum, batch, Wl, bl, out);
}

// Round 16
// 287.213 us; speedup vs baseline: 1.0563x; 1.0175x over previous
//
#include <hip/hip_runtime.h>

#define N_NODES   50000
#define N_EDGES   800000
#define IN_CH     128
#define HID       64
#define N_GRAPHS  64
#define N_CLASSES 2
#define NBLK_SCAN ((N_NODES + 255) / 256)   // 196
#define NREP      32                        // pooledSum replicas
#define FILL_CHUNKS ((N_EDGES + 2047) / 2048)     // 391
#define DEG_BLOCKS (FILL_CHUNKS * 8)              // 3128
#define GEMM_BLOCKS ((N_NODES + 127) / 128)       // 391

// Round 3: single-block scan 133us -> 3-phase scan.
// Round 4: pool 59us @2.3% occupancy -> atomic partial pool + finalize.
// Round 5: fill 54us (16x write amplification) -> XCD-partitioned fill.
// Round 7->8: agg2+pool fusion + 32 replicas (86->47us).
// Round 9/11/13: fill/gemm1 fusion regressed 3x -> abandoned.
// Round 15: float2 agg == 8-wide scalar (44.9 vs 47.4us); round-11's "~40us
// float2 win" was an attribution error. agg2pool: occ 55.7%, VALU 26%,
// 2.1TB/s -> latency-bound w/ degree imbalance (max-of-4 waves per block).
// Round 16: agg blocks 256->64 threads (1 wave = 1 node), grid = 50k.

// ---------------------------------------------------------------------------
// K0: in-degree count, XCD-partitioned + dst-windowed.
// ---------------------------------------------------------------------------
__global__ __launch_bounds__(256) void deg_kernel(const int* __restrict__ ei,
                                                  int* __restrict__ degCount) {
    int part = blockIdx.x & 7;
    int blk  = blockIdx.x >> 3;                   // 0..390
    int lo   = part * 6250;
    int hi   = lo + 6250;
#pragma unroll
    for (int it = 0; it < 8; ++it) {
        int e = blk * 2048 + it * 256 + (int)threadIdx.x;
        if (e < N_EDGES) {
            int dst = ei[N_EDGES + e];
            if (dst >= lo && dst < hi) atomicAdd(&degCount[dst], 1);
        }
    }
}

// ---------------------------------------------------------------------------
// K1a/b/c: 3-phase scan
// ---------------------------------------------------------------------------
__global__ __launch_bounds__(256) void scan1_kernel(const int* __restrict__ degCount,
                                                    int* __restrict__ blockSums) {
    __shared__ int red[256];
    int i = blockIdx.x * 256 + threadIdx.x;
    red[threadIdx.x] = (i < N_NODES) ? degCount[i] : 0;
    __syncthreads();
    for (int off = 128; off > 0; off >>= 1) {
        if (threadIdx.x < off) red[threadIdx.x] += red[threadIdx.x + off];
        __syncthreads();
    }
    if (threadIdx.x == 0) blockSums[blockIdx.x] = red[0];
}

__global__ __launch_bounds__(256) void scan2_kernel(int* __restrict__ blockSums) {
    __shared__ int s[256];
    int t = threadIdx.x;
    int v = (t < NBLK_SCAN) ? blockSums[t] : 0;
    s[t] = v;
    __syncthreads();
    for (int off = 1; off < 256; off <<= 1) {
        int a = (t >= off) ? s[t - off] : 0;
        __syncthreads();
        s[t] += a;
        __syncthreads();
    }
    if (t < NBLK_SCAN) blockSums[t] = s[t] - v;   // exclusive prefix
}

__global__ __launch_bounds__(256) void scan3_kernel(int* __restrict__ degFill,
                                                    const int* __restrict__ blockSums,
                                                    int* __restrict__ rowPtr,
                                                    float* __restrict__ dinv) {
    __shared__ int s[256];
    int t = threadIdx.x;
    int i = blockIdx.x * 256 + t;
    int d = (i < N_NODES) ? degFill[i] : 0;
    s[t] = d;
    __syncthreads();
    for (int off = 1; off < 256; off <<= 1) {
        int a = (t >= off) ? s[t - off] : 0;
        __syncthreads();
        s[t] += a;
        __syncthreads();
    }
    int excl = s[t] - d + blockSums[blockIdx.x];
    if (i < N_NODES) {
        rowPtr[i]  = excl;
        degFill[i] = excl;
        dinv[i]    = 1.0f / sqrtf((float)(d + 1));
    }
    if (i == 0) rowPtr[N_NODES] = N_EDGES;
}

// ---------------------------------------------------------------------------
// K2: CSR fill, XCD-partitioned + dst-windowed (round-5 fix, standalone).
// ---------------------------------------------------------------------------
__global__ __launch_bounds__(256) void fill_kernel(const int* __restrict__ ei,
                                                   int* __restrict__ fillPtr,
                                                   int* __restrict__ colIdx) {
    int part = blockIdx.x & 7;
    int blk  = blockIdx.x >> 3;
    int lo   = part * 6250;
    int hi   = lo + 6250;
#pragma unroll
    for (int it = 0; it < 8; ++it) {
        int e = blk * 2048 + it * 256 + (int)threadIdx.x;
        if (e < N_EDGES) {
            int dst = ei[N_EDGES + e];
            if (dst >= lo && dst < hi) {
                int src = ei[e];
                int pos = atomicAdd(&fillPtr[dst], 1);
                colIdx[pos] = src;
            }
        }
    }
}

// ---------------------------------------------------------------------------
// K3/K5: g = (A @ W) * dinv[row]  (LDS-staged, 8 rows/thread — round-10 form)
// ---------------------------------------------------------------------------
#define FMA4(xs, w, a) { (a).x = fmaf((xs), (w).x, (a).x); \
                         (a).y = fmaf((xs), (w).y, (a).y); \
                         (a).z = fmaf((xs), (w).z, (a).z); \
                         (a).w = fmaf((xs), (w).w, (a).w); }

template <int K>
__global__ __launch_bounds__(256) void gemm_kernel(const float* __restrict__ A,
                                                   const float* __restrict__ W,
                                                   const float* __restrict__ dinv,
                                                   float* __restrict__ out) {
    __shared__ float4 Ws[K * 16];
    for (int i = threadIdx.x; i < K * 16; i += 256)
        Ws[i] = ((const float4*)W)[i];
    __syncthreads();

    const int c4   = threadIdx.x & 15;
    const int rg   = threadIdx.x >> 4;
    const int row0 = blockIdx.x * 128 + rg * 8;

    const float4* ap[8];
#pragma unroll
    for (int r = 0; r < 8; ++r) {
        int rowc = min(row0 + r, N_NODES - 1);
        ap[r] = (const float4*)(A + (size_t)rowc * K);
    }

    float4 acc[8] = {};
    for (int kk = 0; kk < K / 4; ++kk) {
        float4 xv[8];
#pragma unroll
        for (int r = 0; r < 8; ++r) xv[r] = ap[r][kk];
        float4 w;
        w = Ws[(4 * kk + 0) * 16 + c4];
#pragma unroll
        for (int r = 0; r < 8; ++r) FMA4(xv[r].x, w, acc[r]);
        w = Ws[(4 * kk + 1) * 16 + c4];
#pragma unroll
        for (int r = 0; r < 8; ++r) FMA4(xv[r].y, w, acc[r]);
        w = Ws[(4 * kk + 2) * 16 + c4];
#pragma unroll
        for (int r = 0; r < 8; ++r) FMA4(xv[r].z, w, acc[r]);
        w = Ws[(4 * kk + 3) * 16 + c4];
#pragma unroll
        for (int r = 0; r < 8; ++r) FMA4(xv[r].w, w, acc[r]);
    }

#pragma unroll
    for (int r = 0; r < 8; ++r) {
        int row = row0 + r;
        if (row < N_NODES) {
            float dv = dinv[row];
            float4 o = acc[r];
            o.x *= dv; o.y *= dv; o.z *= dv; o.w *= dv;
            ((float4*)(out + (size_t)row * HID))[c4] = o;
        }
    }
}

// ---------------------------------------------------------------------------
// K4: layer-1 aggregation. ONE WAVE PER BLOCK (64 thr), one node per block:
// no intra-block degree-imbalance wait, more independent blocks per CU.
// float2 dual-row gather; halves combined via shfl_xor(32).
// ---------------------------------------------------------------------------
__global__ __launch_bounds__(64) void agg1_kernel(const float* __restrict__ g,
                                                  const float* __restrict__ dinv,
                                                  const int* __restrict__ rowPtr,
                                                  const int* __restrict__ colIdx,
                                                  const float* __restrict__ bias,
                                                  float* __restrict__ out) {
    int lane = threadIdx.x;
    int half = lane >> 5;
    int hl   = lane & 31;
    int v = blockIdx.x;
    if (v >= N_NODES) return;

    const float2* g2 = (const float2*)g;          // row stride = 32 float2
    float2 acc = {0.f, 0.f};
    if (half == 0) acc = g2[(size_t)v * 32 + hl]; // self term (once)

    int e0 = rowPtr[v];
    int e1 = rowPtr[v + 1];
    for (int e = e0; e < e1; e += 16) {
        int   u[8];
        float wsel[8];
#pragma unroll
        for (int k = 0; k < 8; ++k) {
            int ee  = e + 2 * k + half;
            int idx = min(ee, e1 - 1);
            u[k]    = colIdx[idx];
            wsel[k] = (ee < e1) ? 1.f : 0.f;
        }
#pragma unroll
        for (int k = 0; k < 8; ++k) {
            float2 a = g2[(size_t)u[k] * 32 + hl];
            acc.x = fmaf(wsel[k], a.x, acc.x);
            acc.y = fmaf(wsel[k], a.y, acc.y);
        }
    }
    acc.x += __shfl_xor(acc.x, 32);
    acc.y += __shfl_xor(acc.y, 32);

    float dv = dinv[v];
    float2 b = ((const float2*)bias)[hl];
    float2 r;
    r.x = fmaxf(dv * acc.x + b.x, 0.f);
    r.y = fmaxf(dv * acc.y + b.y, 0.f);
    if (half == 0) ((float2*)(out + (size_t)v * HID))[hl] = r;
}

// ---------------------------------------------------------------------------
// K6: layer-2 aggregation + replicated pool atomics. One wave per block.
// ---------------------------------------------------------------------------
__global__ __launch_bounds__(64) void agg2pool_kernel(const float* __restrict__ g,
                                                      const float* __restrict__ dinv,
                                                      const int* __restrict__ rowPtr,
                                                      const int* __restrict__ colIdx,
                                                      const float* __restrict__ bias,
                                                      const int* __restrict__ batch,
                                                      float* __restrict__ pooledSum) {
    int lane = threadIdx.x;
    int half = lane >> 5;
    int hl   = lane & 31;
    int v = blockIdx.x;
    if (v >= N_NODES) return;

    const float2* g2 = (const float2*)g;
    float2 acc = {0.f, 0.f};
    if (half == 0) acc = g2[(size_t)v * 32 + hl];

    int e0 = rowPtr[v];
    int e1 = rowPtr[v + 1];
    for (int e = e0; e < e1; e += 16) {
        int   u[8];
        float wsel[8];
#pragma unroll
        for (int k = 0; k < 8; ++k) {
            int ee  = e + 2 * k + half;
            int idx = min(ee, e1 - 1);
            u[k]    = colIdx[idx];
            wsel[k] = (ee < e1) ? 1.f : 0.f;
        }
#pragma unroll
        for (int k = 0; k < 8; ++k) {
            float2 a = g2[(size_t)u[k] * 32 + hl];
            acc.x = fmaf(wsel[k], a.x, acc.x);
            acc.y = fmaf(wsel[k], a.y, acc.y);
        }
    }
    acc.x += __shfl_xor(acc.x, 32);
    acc.y += __shfl_xor(acc.y, 32);

    float dv = dinv[v];
    float2 b = ((const float2*)bias)[hl];
    float rx = fmaxf(dv * acc.x + b.x, 0.f);
    float ry = fmaxf(dv * acc.y + b.y, 0.f);

    int gid = batch[v];                           // wave-uniform
    int rep = blockIdx.x & (NREP - 1);
    atomicAdd(&pooledSum[(size_t)rep * N_GRAPHS * HID + gid * HID + 2 * hl + half],
              half ? ry : rx);
}

// ---------------------------------------------------------------------------
// K7: finalize. Sums 32 replicas, divides by count, head via shuffle reduce.
// d_out layout: [ out (64x2) | pooled (64x64) ]
// ---------------------------------------------------------------------------
__global__ __launch_bounds__(64) void pool2_kernel(const float* __restrict__ pooledSum,
                                                   const int* __restrict__ batch,
                                                   const float* __restrict__ Wl,
                                                   const float* __restrict__ bl,
                                                   float* __restrict__ dout) {
    int g    = blockIdx.x;
    int lane = threadIdx.x;

    int lo0 = 0, hi = N_NODES;
    while (lo0 < hi) { int mid = (lo0 + hi) >> 1; if (batch[mid] < g) lo0 = mid + 1; else hi = mid; }
    int lo1 = lo0; hi = N_NODES;
    while (lo1 < hi) { int mid = (lo1 + hi) >> 1; if (batch[mid] < g + 1) lo1 = mid + 1; else hi = mid; }
    float cnt = (float)(lo1 - lo0);

    float s = 0.f;
#pragma unroll
    for (int rep = 0; rep < NREP; ++rep)
        s += pooledSum[(size_t)rep * N_GRAPHS * HID + g * HID + lane];

    float p = s / fmaxf(cnt, 1.0f);
    dout[N_GRAPHS * N_CLASSES + g * HID + lane] = p;

    float p0 = p * Wl[lane * N_CLASSES + 0];
    float p1 = p * Wl[lane * N_CLASSES + 1];
#pragma unroll
    for (int off = 32; off > 0; off >>= 1) {
        p0 += __shfl_down(p0, off, 64);
        p1 += __shfl_down(p1, off, 64);
    }
    if (lane == 0) {
        dout[g * N_CLASSES + 0] = p0 + bl[0];
        dout[g * N_CLASSES + 1] = p1 + bl[1];
    }
}

// ---------------------------------------------------------------------------
extern "C" void kernel_launch(void* const* d_in, const int* in_sizes, int n_in,
                              void* d_out, int out_size, void* d_ws, size_t ws_size,
                              hipStream_t stream) {
    const float* x     = (const float*)d_in[0];
    const int*   ei    = (const int*)d_in[1];    // int32 on device
    const int*   batch = (const int*)d_in[2];    // int32 on device
    const float* W1    = (const float*)d_in[3];
    const float* b1    = (const float*)d_in[4];
    const float* W2    = (const float*)d_in[5];
    const float* b2    = (const float*)d_in[6];
    const float* Wl    = (const float*)d_in[7];
    const float* bl    = (const float*)d_in[8];
    float* out = (float*)d_out;

    char* ws = (char*)d_ws;
    size_t off = 0;
    auto alloc = [&](size_t bytes) -> void* {
        void* p = ws + off;
        off += (bytes + 255) & ~(size_t)255;
        return p;
    };
    int*   degFill   = (int*)  alloc((size_t)N_NODES * 4);        // counts -> fillPtr
    int*   rowPtr    = (int*)  alloc((size_t)(N_NODES + 1) * 4);
    float* dinv      = (float*)alloc((size_t)N_NODES * 4);
    int*   blockSums = (int*)  alloc((size_t)NBLK_SCAN * 4);
    float* pooledSum = (float*)alloc((size_t)NREP * N_GRAPHS * HID * 4);  // 512 KB
    int*   colIdx    = (int*)  alloc((size_t)N_EDGES * 4);
    float* bufA      = (float*)alloc((size_t)N_NODES * HID * 4);  // g1, then g2
    float* bufB      = (float*)alloc((size_t)N_NODES * HID * 4);  // h1

    hipMemsetAsync(degFill, 0, (size_t)N_NODES * 4, stream);
    hipMemsetAsync(pooledSum, 0, (size_t)NREP * N_GRAPHS * HID * 4, stream);

    deg_kernel  <<<DEG_BLOCKS, 256, 0, stream>>>(ei, degFill);
    scan1_kernel<<<NBLK_SCAN, 256, 0, stream>>>(degFill, blockSums);
    scan2_kernel<<<1, 256, 0, stream>>>(blockSums);
    scan3_kernel<<<NBLK_SCAN, 256, 0, stream>>>(degFill, blockSums, rowPtr, dinv);
    fill_kernel <<<DEG_BLOCKS, 256, 0, stream>>>(ei, degFill, colIdx);

    // layer 1: g1 = (x@W1)*dinv ; h1 = relu(dinv*(g1[v]+sum g1[u]) + b1)
    gemm_kernel<IN_CH><<<GEMM_BLOCKS, 256, 0, stream>>>(x, W1, dinv, bufA);
    agg1_kernel       <<<N_NODES, 64, 0, stream>>>(bufA, dinv, rowPtr, colIdx, b1, bufB);

    // layer 2: g2 = (h1@W2)*dinv ; h2 row computed in-register, pooled directly
    gemm_kernel<HID><<<GEMM_BLOCKS, 256, 0, stream>>>(bufB, W2, dinv, bufA);
    agg2pool_kernel <<<N_NODES, 64, 0, stream>>>(bufA, dinv, rowPtr, colIdx, b2, batch, pooledSum);

    // finalize pool + head
    pool2_kernel<<<N_GRAPHS, 64, 0, stream>>>(pooledSum, batch, Wl, bl, out);
}